// Round 1
// baseline (806.996 us; speedup 1.0000x reference)
//
#include <hip/hip_runtime.h>
#include <math.h>

// Problem constants (from reference)
#define KTOT  8192
#define WORD  32
#define TDIM  512
#define FRAME 12
#define VDIM  512
#define BATCH 8

#define KSPLIT 512              // k-range splits (grid.y)
#define KPB    (KTOT / KSPLIT)  // 16 k's per block
#define KC     8                // k-chunk held in registers

// float -> order-preserving uint32 (for packed atomicMin argmin)
__device__ __forceinline__ unsigned int f32_sortable(float f) {
    unsigned int u = __float_as_uint(f);
    return (u & 0x80000000u) ? ~u : (u | 0x80000000u);
}

// Precompute log(query) into ws and init packed argmin cells to +inf.
__global__ __launch_bounds__(256) void prep_kernel(const float* __restrict__ query,
                                                   float* __restrict__ logq,
                                                   unsigned long long* __restrict__ packed) {
    int g = blockIdx.x * 256 + threadIdx.x;
    if (g < BATCH * WORD * TDIM) logq[g] = logf(query[g]);
    if (g < BATCH * TDIM) packed[g] = 0xFFFFFFFFFFFFFFFFULL;
}

// score[b,k,d] = sum_w qt*(log qt - log q); running argmin over this block's
// k-range, folded into global packed atomicMin.
// Lane owns one d (coalesced: d is the contiguous axis of qt and logq).
__global__ __launch_bounds__(256) void score_kernel(const float* __restrict__ qt,
                                                    const float* __restrict__ logq,
                                                    unsigned long long* __restrict__ packed) {
    const int d  = blockIdx.x * 256 + threadIdx.x;   // grid.x = 2 covers D=512
    const int k0 = blockIdx.y * KPB;

    float minval[BATCH];
    int   minidx[BATCH];
#pragma unroll
    for (int b = 0; b < BATCH; ++b) { minval[b] = INFINITY; minidx[b] = 0; }

    for (int kc = 0; kc < KPB; kc += KC) {
        float selfa[KC];              // sum_w qt*log(qt)   (batch-independent)
        float cross[BATCH][KC];       // sum_w qt*log(q_b)
#pragma unroll
        for (int kk = 0; kk < KC; ++kk) selfa[kk] = 0.f;
#pragma unroll
        for (int b = 0; b < BATCH; ++b)
#pragma unroll
            for (int kk = 0; kk < KC; ++kk) cross[b][kk] = 0.f;

        for (int w = 0; w < WORD; ++w) {
            // 8 coalesced qt loads (wave-uniform offsets + lane d)
            float q[KC];
#pragma unroll
            for (int kk = 0; kk < KC; ++kk)
                q[kk] = qt[(size_t)(k0 + kc + kk) * (WORD * TDIM) + w * TDIM + d];
            // 8 logq loads, L2-resident (512 KB working set)
            float lq[BATCH];
#pragma unroll
            for (int b = 0; b < BATCH; ++b)
                lq[b] = logq[(b * WORD + w) * TDIM + d];
#pragma unroll
            for (int kk = 0; kk < KC; ++kk)
                selfa[kk] = fmaf(q[kk], logf(q[kk]), selfa[kk]);
#pragma unroll
            for (int b = 0; b < BATCH; ++b)
#pragma unroll
                for (int kk = 0; kk < KC; ++kk)
                    cross[b][kk] = fmaf(q[kk], lq[b], cross[b][kk]);
        }
        // strict < keeps the FIRST (lowest-k) minimum, matching jnp.argmin
#pragma unroll
        for (int b = 0; b < BATCH; ++b)
#pragma unroll
            for (int kk = 0; kk < KC; ++kk) {
                float s = selfa[kk] - cross[b][kk];
                if (s < minval[b]) { minval[b] = s; minidx[b] = k0 + kc + kk; }
            }
    }
    // packed = (sortable(score) << 32) | k  -> atomicMin gives global argmin
    // with lowest-k tie-break (== numpy first-min semantics).
#pragma unroll
    for (int b = 0; b < BATCH; ++b) {
        unsigned long long p = ((unsigned long long)f32_sortable(minval[b]) << 32)
                             | (unsigned long long)(unsigned int)minidx[b];
        atomicMin(&packed[b * TDIM + d], p);
    }
}

// out[b,d,:,:] = queue_video[idx[b,d],:,:] ; one block per (b,d) cell,
// 6144 floats = 1536 float4 copied by 256 threads (6 each), fully coalesced.
__global__ __launch_bounds__(256) void gather_kernel(const float* __restrict__ qv,
                                                     const unsigned long long* __restrict__ packed,
                                                     float* __restrict__ out) {
    const int cell = blockIdx.x;   // b*TDIM + d
    const unsigned int k = (unsigned int)(packed[cell] & 0xFFFFFFFFULL);
    const float4* src = (const float4*)(qv  + (size_t)k    * (FRAME * VDIM));
    float4*       dst = (float4*)      (out + (size_t)cell * (FRAME * VDIM));
#pragma unroll
    for (int i = 0; i < (FRAME * VDIM / 4) / 256; ++i)
        dst[threadIdx.x + i * 256] = src[threadIdx.x + i * 256];
}

extern "C" void kernel_launch(void* const* d_in, const int* in_sizes, int n_in,
                              void* d_out, int out_size, void* d_ws, size_t ws_size,
                              hipStream_t stream) {
    const float* query       = (const float*)d_in[0];  // [8,32,512]
    const float* queue_text  = (const float*)d_in[1];  // [8192,32,512]
    const float* queue_video = (const float*)d_in[2];  // [8192,12,512]
    float* out = (float*)d_out;                        // [8,512,12,512]

    // workspace layout: [0,32KB) packed argmin cells ; [32KB, 32KB+512KB) logq
    unsigned long long* packed = (unsigned long long*)d_ws;
    float* logq = (float*)((char*)d_ws + 32768);

    prep_kernel<<<512, 256, 0, stream>>>(query, logq, packed);
    score_kernel<<<dim3(2, KSPLIT), 256, 0, stream>>>(queue_text, logq, packed);
    gather_kernel<<<BATCH * TDIM, 256, 0, stream>>>(queue_video, packed, out);
}